// Round 1
// baseline (412.650 us; speedup 1.0000x reference)
//
#include <hip/hip_runtime.h>
#include <cmath>

#define N_MET   100000
#define N_RXN   200000
#define E_SUB   400000
#define E_PROD  400000
#define HIDDEN  128
#define MSG_DIM 64
#define DT      0.01f
#define TGRID   96
#define TGP     97

__device__ __forceinline__ float fast_tanh(float x) {
    float t = __expf(2.0f * x);
    return 1.0f - 2.0f * __builtin_amdgcn_rcpf(t + 1.0f);
}

__device__ __forceinline__ float softplus_f(float x) {
    return (x > 20.0f) ? x : log1pf(__expf(x));
}

__global__ void init_kernel(float* __restrict__ rxn_scale) {
    int i = blockIdx.x * blockDim.x + threadIdx.x;
    if (i < N_RXN) rxn_scale[i] = 1.0f;
}

// One block (64 threads) per table grid point. msg_table[(ia*TGP+ib)*64 + m]
// = b2[m] + sum_j tanh(a*W1[0][j] + b*W1[1][j] + b1[j]) * W2[j][m]
__global__ void build_table(const float* __restrict__ W1, const float* __restrict__ b1,
                            const float* __restrict__ W2, const float* __restrict__ b2,
                            float* __restrict__ table) {
    __shared__ float h_s[HIDDEN];
    int p = blockIdx.x;
    int ia = p / TGP, ib = p % TGP;
    float a = (float)ia * (1.0f / TGRID);
    float b = 0.5f + (float)ib * (1.0f / TGRID);
    int lane = threadIdx.x;
    for (int j = lane; j < HIDDEN; j += 64)
        h_s[j] = tanhf(fmaf(a, W1[j], fmaf(b, W1[HIDDEN + j], b1[j])));
    __syncthreads();
    float msg = b2[lane];
    #pragma unroll 8
    for (int j = 0; j < HIDDEN; ++j)
        msg = fmaf(h_s[j], W2[j * MSG_DIM + lane], msg);
    table[p * MSG_DIM + lane] = msg;
}

// Wave handles 64 edges per chunk: coalesced loads of per-edge scalars, then
// per edge: bilinear interp of 64-dim msg (lane = m), atomicAdd into h_rxn.
__global__ void edge_kernel(const float* __restrict__ x,
                            const int* __restrict__ met_sub,
                            const int* __restrict__ rxn_sub,
                            const float* __restrict__ sto_sub,
                            const float* __restrict__ table,
                            float* __restrict__ h_rxn,
                            float* __restrict__ ext_sum,
                            float* __restrict__ cnt) {
    int lane = threadIdx.x & 63;
    int wave = (blockIdx.x * blockDim.x + threadIdx.x) >> 6;
    int nwaves = (gridDim.x * blockDim.x) >> 6;
    for (int e0 = wave * 64; e0 < E_SUB; e0 += nwaves * 64) {
        int e = e0 + lane;                  // E_SUB % 64 == 0, always valid
        int   me = met_sub[e];
        int   re = rxn_sub[e];
        float se = sto_sub[e];
        float ae = x[me * 8 + 3];           // conc
        float xe = x[me * 8 + 4];           // ext
        for (int i = 0; i < 64; ++i) {
            float a = __shfl(ae, i);
            float b = __shfl(se, i);
            int   r = __shfl(re, i);
            float fa = a * (float)TGRID;
            float fb = (b - 0.5f) * (float)TGRID;
            int ia = (int)fa; ia = (ia < 0) ? 0 : ((ia > TGRID - 1) ? TGRID - 1 : ia);
            int ib = (int)fb; ib = (ib < 0) ? 0 : ((ib > TGRID - 1) ? TGRID - 1 : ib);
            float wa = fa - (float)ia;
            float wb = fb - (float)ib;
            const float* t00 = table + (ia * TGP + ib) * MSG_DIM;
            float m00 = t00[lane];
            float m01 = t00[MSG_DIM + lane];
            float m10 = t00[TGP * MSG_DIM + lane];
            float m11 = t00[(TGP + 1) * MSG_DIM + lane];
            float m0  = fmaf(wb, m01 - m00, m00);
            float m1  = fmaf(wb, m11 - m10, m10);
            float msg = fmaf(wa, m1 - m0, m0);
            atomicAdd(&h_rxn[r * MSG_DIM + lane], msg);
        }
        atomicAdd(&ext_sum[re], xe);
        atomicAdd(&cnt[re], 1.0f);
    }
}

// Wave processes 2 reactions per iteration. V1 columns (t=lane, t=lane+64)
// live in 128 registers; h broadcast via LDS float4 reads.
__global__ void __launch_bounds__(256, 2)
rxn_kernel(const float* __restrict__ h_rxn,
           const float* __restrict__ V1, const float* __restrict__ c1,
           const float* __restrict__ V2, const float* __restrict__ c2,
           const float* __restrict__ log_k,
           const float* __restrict__ ext_sum, const float* __restrict__ cnt,
           float* __restrict__ v_out) {
    __shared__ float h_s[4][2][MSG_DIM];
    int lane  = threadIdx.x & 63;
    int wslot = threadIdx.x >> 6;
    float v1a[64], v1b[64];
    #pragma unroll
    for (int d = 0; d < 64; ++d) {
        v1a[d] = V1[d * HIDDEN + lane];
        v1b[d] = V1[d * HIDDEN + 64 + lane];
    }
    float v2a = V2[lane], v2b = V2[64 + lane];
    float c1a = c1[lane], c1b = c1[64 + lane];
    float c2v = c2[0];
    int wave = (blockIdx.x * blockDim.x + threadIdx.x) >> 6;
    int nwaves = (gridDim.x * blockDim.x) >> 6;
    for (int r0 = wave * 2; r0 < N_RXN; r0 += nwaves * 2) {
        h_s[wslot][0][lane] = h_rxn[r0 * MSG_DIM + lane];
        h_s[wslot][1][lane] = h_rxn[(r0 + 1) * MSG_DIM + lane];
        float z0a = c1a, z0b = c1b, z1a = c1a, z1b = c1b;
        #pragma unroll
        for (int d4 = 0; d4 < 64; d4 += 4) {
            float4 h0 = *(const float4*)&h_s[wslot][0][d4];
            float4 h1 = *(const float4*)&h_s[wslot][1][d4];
            z0a = fmaf(h0.x, v1a[d4 + 0], z0a); z0b = fmaf(h0.x, v1b[d4 + 0], z0b);
            z0a = fmaf(h0.y, v1a[d4 + 1], z0a); z0b = fmaf(h0.y, v1b[d4 + 1], z0b);
            z0a = fmaf(h0.z, v1a[d4 + 2], z0a); z0b = fmaf(h0.z, v1b[d4 + 2], z0b);
            z0a = fmaf(h0.w, v1a[d4 + 3], z0a); z0b = fmaf(h0.w, v1b[d4 + 3], z0b);
            z1a = fmaf(h1.x, v1a[d4 + 0], z1a); z1b = fmaf(h1.x, v1b[d4 + 0], z1b);
            z1a = fmaf(h1.y, v1a[d4 + 1], z1a); z1b = fmaf(h1.y, v1b[d4 + 1], z1b);
            z1a = fmaf(h1.z, v1a[d4 + 2], z1a); z1b = fmaf(h1.z, v1b[d4 + 2], z1b);
            z1a = fmaf(h1.w, v1a[d4 + 3], z1a); z1b = fmaf(h1.w, v1b[d4 + 3], z1b);
        }
        float p0 = fast_tanh(z0a) * v2a + fast_tanh(z0b) * v2b;
        float p1 = fast_tanh(z1a) * v2a + fast_tanh(z1b) * v2b;
        #pragma unroll
        for (int off = 32; off > 0; off >>= 1) {
            p0 += __shfl_xor(p0, off);
            p1 += __shfl_xor(p1, off);
        }
        if (lane < 2) {
            int r = r0 + lane;
            float p = (lane == 0) ? p0 : p1;
            float bv = softplus_f(p + c2v);
            float k  = __expf(log_k[r] * 2.302585092994046f);   // 10^log_k
            float em = ext_sum[r] / fmaxf(cnt[r], 1.0f);
            v_out[r] = k * em * bv;
        }
    }
}

__global__ void cons_kernel(const int* __restrict__ met_sub, const int* __restrict__ rxn_sub,
                            const float* __restrict__ sto_sub, const float* __restrict__ v,
                            float* __restrict__ tot) {
    int e = blockIdx.x * blockDim.x + threadIdx.x;
    if (e < E_SUB)
        atomicAdd(&tot[met_sub[e]], sto_sub[e] * v[rxn_sub[e]] * DT);
}

__global__ void met_scale_kernel(const float* __restrict__ x, const float* __restrict__ tot,
                                 float* __restrict__ ms) {
    int i = blockIdx.x * blockDim.x + threadIdx.x;
    if (i < N_MET) {
        float tc = tot[i];
        float conc = x[i * 8 + 3];
        ms[i] = (tc > 1e-12f) ? fminf(conc / tc, 1.0f) : 1.0f;
    }
}

__global__ void rxn_min_kernel(const int* __restrict__ met_sub, const int* __restrict__ rxn_sub,
                               const float* __restrict__ ms, float* __restrict__ rxn_scale) {
    int e = blockIdx.x * blockDim.x + threadIdx.x;
    if (e < E_SUB) {
        float s = ms[met_sub[e]];
        // met_scale is always in [0,1] (non-negative) -> uint compare == float compare
        atomicMin((unsigned int*)&rxn_scale[rxn_sub[e]], __float_as_uint(s));
    }
}

__global__ void vscale_kernel(float* __restrict__ v, const float* __restrict__ rxn_scale) {
    int r = blockIdx.x * blockDim.x + threadIdx.x;
    if (r < N_RXN) v[r] *= rxn_scale[r];
}

__global__ void out_kernel(const int* __restrict__ met_sub, const int* __restrict__ rxn_sub,
                           const float* __restrict__ sto_sub,
                           const int* __restrict__ met_prod, const int* __restrict__ rxn_prod,
                           const float* __restrict__ sto_prod,
                           const float* __restrict__ v, float* __restrict__ out) {
    int t = blockIdx.x * blockDim.x + threadIdx.x;
    if (t < E_SUB) {
        atomicAdd(&out[met_sub[t]], -sto_sub[t] * v[rxn_sub[t]]);
    } else if (t < E_SUB + E_PROD) {
        int e = t - E_SUB;
        atomicAdd(&out[met_prod[e]], sto_prod[e] * v[rxn_prod[e]]);
    }
}

extern "C" void kernel_launch(void* const* d_in, const int* in_sizes, int n_in,
                              void* d_out, int out_size, void* d_ws, size_t ws_size,
                              hipStream_t stream) {
    const float* x        = (const float*)d_in[0];
    const int*   met_sub  = (const int*)d_in[1];
    const int*   rxn_sub  = (const int*)d_in[2];
    const float* sto_sub  = (const float*)d_in[3];
    const int*   met_prod = (const int*)d_in[4];
    const int*   rxn_prod = (const int*)d_in[5];
    const float* sto_prod = (const float*)d_in[6];
    const float* W1       = (const float*)d_in[7];
    const float* b1       = (const float*)d_in[8];
    const float* W2       = (const float*)d_in[9];
    const float* b2       = (const float*)d_in[10];
    const float* V1       = (const float*)d_in[11];
    const float* c1       = (const float*)d_in[12];
    const float* V2       = (const float*)d_in[13];
    const float* c2       = (const float*)d_in[14];
    const float* log_k    = (const float*)d_in[15];

    float* ws        = (float*)d_ws;
    float* h_rxn     = ws;                                   // N_RXN*64
    float* ext_sum   = h_rxn + (size_t)N_RXN * MSG_DIM;      // N_RXN
    float* cnt       = ext_sum + N_RXN;                      // N_RXN
    float* tot       = cnt + N_RXN;                          // N_MET
    float* v         = tot + N_MET;                          // N_RXN
    float* ms        = v + N_RXN;                            // N_MET
    float* rxn_scale = ms + N_MET;                           // N_RXN
    float* table     = rxn_scale + N_RXN;                    // TGP*TGP*64

    size_t zero_floats = (size_t)N_RXN * MSG_DIM + N_RXN + N_RXN + N_MET;
    hipMemsetAsync(h_rxn, 0, zero_floats * sizeof(float), stream);
    hipMemsetAsync(d_out, 0, (size_t)N_MET * sizeof(float), stream);

    init_kernel<<<(N_RXN + 255) / 256, 256, 0, stream>>>(rxn_scale);
    build_table<<<TGP * TGP, 64, 0, stream>>>(W1, b1, W2, b2, table);
    edge_kernel<<<1563, 256, 0, stream>>>(x, met_sub, rxn_sub, sto_sub, table,
                                          h_rxn, ext_sum, cnt);
    rxn_kernel<<<768, 256, 0, stream>>>(h_rxn, V1, c1, V2, c2, log_k, ext_sum, cnt, v);
    cons_kernel<<<(E_SUB + 255) / 256, 256, 0, stream>>>(met_sub, rxn_sub, sto_sub, v, tot);
    met_scale_kernel<<<(N_MET + 255) / 256, 256, 0, stream>>>(x, tot, ms);
    rxn_min_kernel<<<(E_SUB + 255) / 256, 256, 0, stream>>>(met_sub, rxn_sub, ms, rxn_scale);
    vscale_kernel<<<(N_RXN + 255) / 256, 256, 0, stream>>>(v, rxn_scale);
    out_kernel<<<(E_SUB + E_PROD + 255) / 256, 256, 0, stream>>>(
        met_sub, rxn_sub, sto_sub, met_prod, rxn_prod, sto_prod, v, (float*)d_out);
}